// Round 1
// 3409.261 us; speedup vs baseline: 3.3727x; 3.3727x over previous
//
#include <hip/hip_runtime.h>
#include <hip/hip_bf16.h>
#include <math.h>

// Problem constants (from reference)
#define NLAYERS 6
#define HEADS   16
#define CDIM    1024
#define HDIM    64
#define VOCAB   32000
#define TSEQ    1024
#define BATCH   2
#define ROWS    (BATCH*TSEQ)   // 2048
#define DFFDIM  4096

typedef __attribute__((ext_vector_type(8))) short  short8;
typedef __attribute__((ext_vector_type(4))) float  floatx4;

__device__ __forceinline__ short f2bs(float f) {
    __hip_bfloat16 h = __float2bfloat16(f);
    return *reinterpret_cast<short*>(&h);
}

// ---------------------------------------------------------------- embedding
__global__ __launch_bounds__(256) void embed_kernel(
    const int* __restrict__ idx, const float* __restrict__ wte,
    const float* __restrict__ wpe, float* __restrict__ x)
{
    int r = blockIdx.x;             // 0..2047
    int tok = idx[r];
    int pos = r & (TSEQ - 1);
    const float4* a = (const float4*)(wte + (size_t)tok * CDIM);
    const float4* p = (const float4*)(wpe + (size_t)pos * CDIM);
    float4* o = (float4*)(x + (size_t)r * CDIM);
    int t = threadIdx.x;            // CDIM/4 == 256
    float4 av = a[t], pv = p[t];
    o[t] = make_float4(av.x + pv.x, av.y + pv.y, av.z + pv.z, av.w + pv.w);
}

// ---------------------------------------------------------------- layernorm
__global__ __launch_bounds__(256) void ln_kernel(
    const float* __restrict__ x, const float* __restrict__ g,
    const float* __restrict__ b, __hip_bfloat16* __restrict__ out)
{
    int r = blockIdx.x;
    int t = threadIdx.x;
    const float* xr = x + (size_t)r * CDIM;
    float v[4];
#pragma unroll
    for (int i = 0; i < 4; i++) v[i] = xr[t + i * 256];

    __shared__ float red[4];
    int w = t >> 6, lane = t & 63;

    float s = v[0] + v[1] + v[2] + v[3];
    for (int off = 32; off; off >>= 1) s += __shfl_xor(s, off);
    if (lane == 0) red[w] = s;
    __syncthreads();
    float mean = (red[0] + red[1] + red[2] + red[3]) * (1.0f / CDIM);

    float s2 = 0.0f;
#pragma unroll
    for (int i = 0; i < 4; i++) { float d = v[i] - mean; s2 += d * d; }
    for (int off = 32; off; off >>= 1) s2 += __shfl_xor(s2, off);
    __syncthreads();
    if (lane == 0) red[w] = s2;
    __syncthreads();
    float var = (red[0] + red[1] + red[2] + red[3]) * (1.0f / CDIM);
    float rstd = rsqrtf(var + 1e-5f);

#pragma unroll
    for (int i = 0; i < 4; i++) {
        int c = t + i * 256;
        out[(size_t)r * CDIM + c] =
            __float2bfloat16((v[i] - mean) * rstd * g[c] + b[c]);
    }
}

// ---------------------------------------------------------------- GEMM
// C[M,N] = A[M,K](bf16) @ B (fp32 weights, cast to bf16 in staging)
// BNT=false: B is [K,N] row-major.  BNT=true: B is [N,K] row-major.
// Epilogue: +bias, gelu(exact), +resid (fp32), store fp32 (Cf) or bf16 (Cb).
template <bool BNT>
__global__ __launch_bounds__(256) void gemm_kernel(
    const __hip_bfloat16* __restrict__ A, const float* __restrict__ B,
    float* __restrict__ Cf, __hip_bfloat16* __restrict__ Cb,
    const float* __restrict__ bias, const float* __restrict__ resid,
    int M, int N, int K, int do_gelu)
{
    __shared__ __align__(16) __hip_bfloat16 As[64][32];
    __shared__ __align__(16) __hip_bfloat16 Bs[2048]; // NT:[n][k]=64x32, NN:[k][n]=32x64

    int t = threadIdx.x;
    int n0 = blockIdx.x * 64, m0 = blockIdx.y * 64;
    int w = t >> 6, lane = t & 63, quad = lane >> 4, l16 = lane & 15;

    floatx4 acc[4];
#pragma unroll
    for (int i = 0; i < 4; i++) acc[i] = (floatx4){0.f, 0.f, 0.f, 0.f};

    int ar = t >> 2, ac = (t & 3) * 8;   // A staging: 64 rows x 32 cols, 8/thread

    for (int k0 = 0; k0 < K; k0 += 32) {
        // stage A (bf16, 16B vector copy)
        *(uint4*)&As[ar][ac] =
            *(const uint4*)(A + (size_t)(m0 + ar) * K + k0 + ac);

        // stage B (fp32 -> bf16)
        if (BNT) {
            const float* src = B + (size_t)(n0 + ar) * K + k0 + ac;
            float4 f0 = *(const float4*)(src);
            float4 f1 = *(const float4*)(src + 4);
            short8 pk;
            pk[0] = f2bs(f0.x); pk[1] = f2bs(f0.y); pk[2] = f2bs(f0.z); pk[3] = f2bs(f0.w);
            pk[4] = f2bs(f1.x); pk[5] = f2bs(f1.y); pk[6] = f2bs(f1.z); pk[7] = f2bs(f1.w);
            *(short8*)&Bs[ar * 32 + ac] = pk;
        } else {
            int br = t >> 3, bc = (t & 7) * 8;  // 32 rows x 64 cols
            const float* src = B + (size_t)(k0 + br) * N + n0 + bc;
            float4 f0 = *(const float4*)(src);
            float4 f1 = *(const float4*)(src + 4);
            short8 pk;
            pk[0] = f2bs(f0.x); pk[1] = f2bs(f0.y); pk[2] = f2bs(f0.z); pk[3] = f2bs(f0.w);
            pk[4] = f2bs(f1.x); pk[5] = f2bs(f1.y); pk[6] = f2bs(f1.z); pk[7] = f2bs(f1.w);
            *(short8*)&Bs[br * 64 + bc] = pk;
        }
        __syncthreads();

        short8 a = *(const short8*)&As[w * 16 + l16][quad * 8];
#pragma unroll
        for (int nt = 0; nt < 4; nt++) {
            short8 bfr;
            if (BNT) {
                bfr = *(const short8*)&Bs[(nt * 16 + l16) * 32 + quad * 8];
            } else {
#pragma unroll
                for (int j = 0; j < 8; j++)
                    bfr[j] = ((const short*)Bs)[(quad * 8 + j) * 64 + nt * 16 + l16];
            }
            acc[nt] = __builtin_amdgcn_mfma_f32_16x16x32_bf16(a, bfr, acc[nt], 0, 0, 0);
        }
        __syncthreads();
    }

    // epilogue: D row = w*16 + quad*4 + r, col = nt*16 + l16
#pragma unroll
    for (int nt = 0; nt < 4; nt++) {
        int gn = n0 + nt * 16 + l16;
        float bv = bias ? bias[gn] : 0.0f;
#pragma unroll
        for (int r = 0; r < 4; r++) {
            int gm = m0 + w * 16 + quad * 4 + r;
            float v = acc[nt][r] + bv;
            if (do_gelu) v = 0.5f * v * (1.0f + erff(v * 0.70710678118654752f));
            if (resid) v += resid[(size_t)gm * N + gn];
            if (Cf) Cf[(size_t)gm * N + gn] = v;
            else    Cb[(size_t)gm * N + gn] = __float2bfloat16(v);
        }
    }
}

// ---------------------------------------------------------------- attention
// Flash-attention with MFMA. One block = one (b,h) x 64 Q-rows; 4 waves,
// each wave owns 16 Q-rows. Online softmax in MFMA D-layout, wave-parallel
// row-reduce via __shfl_xor over the 16-lane column group.
#define KSTR 72   // K LDS row stride (elems): 144B, 16B-aligned, slot-balanced
#define VSTR 66   // V LDS row stride: 132B -> (33k + d/2) mod 32 covers all banks
#define PSTR 72

__global__ __launch_bounds__(256) void attn_kernel(
    const __hip_bfloat16* __restrict__ qkvh, __hip_bfloat16* __restrict__ y)
{
    const short* qkv = (const short*)qkvh;
    __shared__ __align__(16) short Ks[64 * KSTR];
    __shared__ __align__(16) short Vs[64 * VSTR];
    __shared__ __align__(16) short Ps[4][16 * PSTR];   // per-wave P buffer

    int id = blockIdx.x;
    int bh = id & 31;             // (b,h): 2*16 = 32
    int qi = 15 - (id >> 5);      // q-tile, heaviest (most K-tiles) first
    int h = bh & 15, b = bh >> 4;

    int t = threadIdx.x;
    int w = t >> 6, lane = t & 63, g = lane >> 4, l15 = lane & 15;

    const size_t base = (size_t)b * TSEQ * (3 * CDIM);
    const int q0 = qi * 64;
    const int qw = q0 + w * 16;   // wave's first q-row

    // Q fragments in registers: lane holds Q[qw+l15][ks*32 + g*8 + j]
    short8 qf[2];
    {
        const short* qp = qkv + base + (size_t)(qw + l15) * (3 * CDIM) + h * HDIM + g * 8;
        qf[0] = *(const short8*)qp;
        qf[1] = *(const short8*)(qp + 32);
    }

    const short* kp = qkv + base + CDIM + h * HDIM;
    const short* vp = kp + CDIM;

    floatx4 o[4];
    float m[4], lsum[4];
#pragma unroll
    for (int i = 0; i < 4; ++i) {
        o[i] = (floatx4){0.f, 0.f, 0.f, 0.f};
        m[i] = -1e30f; lsum[i] = 0.f;
    }

    short* pw = &Ps[w][0];

    for (int kt = 0; kt <= qi; ++kt) {
        const int k0 = kt * 64;
        __syncthreads();           // prev tile fully consumed
        // stage K,V tile: 64 rows x 128B = 512 x 16B chunks, 2 per thread
#pragma unroll
        for (int c0 = 0; c0 < 2; ++c0) {
            int c = t + c0 * 256;
            int row = c >> 3, off = (c & 7) * 8;
            *(short8*)&Ks[row * KSTR + off] =
                *(const short8*)(kp + (size_t)(k0 + row) * (3 * CDIM) + off);
            union { short8 s; unsigned u[4]; } vv;
            vv.s = *(const short8*)(vp + (size_t)(k0 + row) * (3 * CDIM) + off);
            unsigned* vd = (unsigned*)&Vs[row * VSTR + off];  // 4B-aligned
#pragma unroll
            for (int j = 0; j < 4; ++j) vd[j] = vv.u[j];
        }
        __syncthreads();

        // S = Q K^T : 16x64 in 4 D-frags; lane holds S[4g+r][nt*16+l15]
        floatx4 s[4];
#pragma unroll
        for (int nt = 0; nt < 4; ++nt) s[nt] = (floatx4){0.f, 0.f, 0.f, 0.f};
#pragma unroll
        for (int ks = 0; ks < 2; ++ks) {
#pragma unroll
            for (int nt = 0; nt < 4; ++nt) {
                short8 kf = *(const short8*)&Ks[(nt * 16 + l15) * KSTR + ks * 32 + g * 8];
                s[nt] = __builtin_amdgcn_mfma_f32_16x16x32_bf16(qf[ks], kf, s[nt], 0, 0, 0);
            }
        }

        // scale + causal mask (diagonal tile only)
        const float scale = 0.125f;   // 1/sqrt(64)
        if (kt == qi) {
#pragma unroll
            for (int nt = 0; nt < 4; ++nt) {
                int kk = k0 + nt * 16 + l15;
#pragma unroll
                for (int r = 0; r < 4; ++r) {
                    int qq = qw + 4 * g + r;
                    s[nt][r] = (kk <= qq) ? s[nt][r] * scale : -1e30f;
                }
            }
        } else {
#pragma unroll
            for (int nt = 0; nt < 4; ++nt)
#pragma unroll
                for (int r = 0; r < 4; ++r) s[nt][r] *= scale;
        }

        // wave-parallel row max over 64 keys (4 frags in-lane + xor over 16 lanes)
        float mk[4];
#pragma unroll
        for (int r = 0; r < 4; ++r)
            mk[r] = fmaxf(fmaxf(s[0][r], s[1][r]), fmaxf(s[2][r], s[3][r]));
#pragma unroll
        for (int off = 1; off < 16; off <<= 1)
#pragma unroll
            for (int r = 0; r < 4; ++r)
                mk[r] = fmaxf(mk[r], __shfl_xor(mk[r], off));

        float corr[4], psum[4];
#pragma unroll
        for (int r = 0; r < 4; ++r) {
            float mn = fmaxf(m[r], mk[r]);
            corr[r] = __expf(m[r] - mn);
            m[r] = mn;
            psum[r] = 0.f;
        }
#pragma unroll
        for (int nt = 0; nt < 4; ++nt)
#pragma unroll
            for (int r = 0; r < 4; ++r) {
                float p = __expf(s[nt][r] - m[r]);
                s[nt][r] = p;
                psum[r] += p;
            }
#pragma unroll
        for (int off = 1; off < 16; off <<= 1)
#pragma unroll
            for (int r = 0; r < 4; ++r) psum[r] += __shfl_xor(psum[r], off);
#pragma unroll
        for (int r = 0; r < 4; ++r) lsum[r] = lsum[r] * corr[r] + psum[r];
#pragma unroll
        for (int nt = 0; nt < 4; ++nt)
#pragma unroll
            for (int r = 0; r < 4; ++r) o[nt][r] *= corr[r];

        // P (D-layout) -> wave-private LDS as bf16 (A-fragment transpose)
#pragma unroll
        for (int nt = 0; nt < 4; ++nt)
#pragma unroll
            for (int r = 0; r < 4; ++r)
                pw[(4 * g + r) * PSTR + nt * 16 + l15] = f2bs(s[nt][r]);

        // O += P V
#pragma unroll
        for (int ks = 0; ks < 2; ++ks) {
            short8 pf = *(const short8*)&pw[l15 * PSTR + ks * 32 + g * 8];
#pragma unroll
            for (int nt = 0; nt < 4; ++nt) {
                short8 vf;
#pragma unroll
                for (int j = 0; j < 8; ++j)
                    vf[j] = Vs[(ks * 32 + g * 8 + j) * VSTR + nt * 16 + l15];
                o[nt] = __builtin_amdgcn_mfma_f32_16x16x32_bf16(pf, vf, o[nt], 0, 0, 0);
            }
        }
    }

    // epilogue: y[b, q, h*64 + d] = o / lsum
#pragma unroll
    for (int r = 0; r < 4; ++r) {
        float inv = 1.0f / lsum[r];
        int gq = qw + 4 * g + r;
        __hip_bfloat16* yr = y + (size_t)(b * TSEQ + gq) * CDIM + h * HDIM;
#pragma unroll
        for (int nt = 0; nt < 4; ++nt)
            yr[nt * 16 + l15] = __float2bfloat16(o[nt][r] * inv);
    }
}

// ---------------------------------------------------------------- loss
__global__ __launch_bounds__(256) void loss_rows_kernel(
    const float* __restrict__ logits, const int* __restrict__ targets,
    float* __restrict__ out)
{
    int r = blockIdx.x, t = threadIdx.x;
    const float* row = logits + (size_t)r * VOCAB;
    __shared__ float red[4];
    int w = t >> 6, lane = t & 63;

    float mx = -1e30f;
    for (int c = t; c < VOCAB; c += 256) mx = fmaxf(mx, row[c]);
    for (int off = 32; off; off >>= 1) mx = fmaxf(mx, __shfl_xor(mx, off));
    if (lane == 0) red[w] = mx;
    __syncthreads();
    mx = fmaxf(fmaxf(red[0], red[1]), fmaxf(red[2], red[3]));

    float s = 0.0f;
    for (int c = t; c < VOCAB; c += 256) s += __expf(row[c] - mx);
    for (int off = 32; off; off >>= 1) s += __shfl_xor(s, off);
    __syncthreads();
    if (lane == 0) red[w] = s;
    __syncthreads();
    s = red[0] + red[1] + red[2] + red[3];

    if (t == 0) out[r] = logf(s) + mx - row[targets[r]];
}

__global__ __launch_bounds__(256) void loss_final_kernel(
    const float* __restrict__ lr, float* __restrict__ out)
{
    int t = threadIdx.x;
    float s = 0.0f;
    for (int c = t; c < ROWS; c += 256) s += lr[c];
    for (int off = 32; off; off >>= 1) s += __shfl_xor(s, off);
    __shared__ float red[4];
    int w = t >> 6, lane = t & 63;
    if (lane == 0) red[w] = s;
    __syncthreads();
    if (t == 0) out[0] = (red[0] + red[1] + red[2] + red[3]) * (1.0f / ROWS);
}

// ---------------------------------------------------------------- launch
extern "C" void kernel_launch(void* const* d_in, const int* in_sizes, int n_in,
                              void* d_out, int out_size, void* d_ws, size_t ws_size,
                              hipStream_t stream)
{
    const int*   idx     = (const int*)d_in[0];
    const int*   targets = (const int*)d_in[1];
    const float* wte     = (const float*)d_in[2];
    const float* wpe     = (const float*)d_in[3];
    const float* ln1_g   = (const float*)d_in[4];
    const float* ln1_b   = (const float*)d_in[5];
    const float* qkv_w   = (const float*)d_in[6];
    const float* aproj_w = (const float*)d_in[7];
    const float* ln2_g   = (const float*)d_in[8];
    const float* ln2_b   = (const float*)d_in[9];
    const float* fc_w    = (const float*)d_in[10];
    const float* fc_b    = (const float*)d_in[11];
    const float* mproj_w = (const float*)d_in[12];
    const float* mproj_b = (const float*)d_in[13];
    const float* lnf_g   = (const float*)d_in[14];
    const float* lnf_b   = (const float*)d_in[15];

    char* p = (char*)d_ws;
    float* x             = (float*)p;           p += (size_t)ROWS * CDIM * 4;
    __hip_bfloat16* qkvb = (__hip_bfloat16*)p;  p += (size_t)ROWS * 3 * CDIM * 2;
    __hip_bfloat16* h_bf = (__hip_bfloat16*)p;  p += (size_t)ROWS * CDIM * 2;
    __hip_bfloat16* g_bf = (__hip_bfloat16*)p;  p += (size_t)ROWS * DFFDIM * 2;
    __hip_bfloat16* y_bf = (__hip_bfloat16*)p;  p += (size_t)ROWS * CDIM * 2;
    float* lrow          = (float*)p;           p += (size_t)ROWS * 4;

    float* logits = (float*)d_out;

    embed_kernel<<<ROWS, 256, 0, stream>>>(idx, wte, wpe, x);

    for (int l = 0; l < NLAYERS; l++) {
        ln_kernel<<<ROWS, 256, 0, stream>>>(x, ln1_g + l * CDIM, ln1_b + l * CDIM, h_bf);
        gemm_kernel<false><<<dim3(3 * CDIM / 64, ROWS / 64), 256, 0, stream>>>(
            h_bf, qkv_w + (size_t)l * CDIM * 3 * CDIM, nullptr, qkvb,
            nullptr, nullptr, ROWS, 3 * CDIM, CDIM, 0);
        attn_kernel<<<32 * (TSEQ / 64), 256, 0, stream>>>(qkvb, y_bf);
        gemm_kernel<false><<<dim3(CDIM / 64, ROWS / 64), 256, 0, stream>>>(
            y_bf, aproj_w + (size_t)l * CDIM * CDIM, x, nullptr,
            nullptr, x, ROWS, CDIM, CDIM, 0);
        ln_kernel<<<ROWS, 256, 0, stream>>>(x, ln2_g + l * CDIM, ln2_b + l * CDIM, h_bf);
        gemm_kernel<false><<<dim3(DFFDIM / 64, ROWS / 64), 256, 0, stream>>>(
            h_bf, fc_w + (size_t)l * CDIM * DFFDIM, nullptr, g_bf,
            fc_b + l * DFFDIM, nullptr, ROWS, DFFDIM, CDIM, 1);
        gemm_kernel<false><<<dim3(CDIM / 64, ROWS / 64), 256, 0, stream>>>(
            g_bf, mproj_w + (size_t)l * DFFDIM * CDIM, x, nullptr,
            mproj_b + l * CDIM, x, ROWS, CDIM, DFFDIM, 0);
    }

    ln_kernel<<<ROWS, 256, 0, stream>>>(x, lnf_g, lnf_b, h_bf);
    gemm_kernel<true><<<dim3(VOCAB / 64, ROWS / 64), 256, 0, stream>>>(
        h_bf, wte, logits, nullptr, nullptr, nullptr, ROWS, VOCAB, CDIM, 0);

    loss_rows_kernel<<<ROWS, 256, 0, stream>>>(logits, targets, lrow);
    loss_final_kernel<<<1, 256, 0, stream>>>(lrow, logits + (size_t)ROWS * VOCAB);
}

// Round 2
// 2283.920 us; speedup vs baseline: 5.0345x; 1.4927x over previous
//
#include <hip/hip_runtime.h>
#include <hip/hip_bf16.h>
#include <math.h>

// Problem constants (from reference)
#define NLAYERS 6
#define HEADS   16
#define CDIM    1024
#define HDIM    64
#define VOCAB   32000
#define TSEQ    1024
#define BATCH   2
#define ROWS    (BATCH*TSEQ)   // 2048
#define DFFDIM  4096

typedef __attribute__((ext_vector_type(8))) short  short8;
typedef __attribute__((ext_vector_type(4))) float  floatx4;

__device__ __forceinline__ short f2bs(float f) {
    __hip_bfloat16 h = __float2bfloat16(f);
    return *reinterpret_cast<short*>(&h);
}

// async global->LDS, 16B per lane. LDS dest must be wave-uniform-base + lane*16.
__device__ __forceinline__ void gload_lds16(const void* g, void* l) {
    __builtin_amdgcn_global_load_lds(
        (const __attribute__((address_space(1))) unsigned int*)g,
        (__attribute__((address_space(3))) unsigned int*)l, 16, 0, 0);
}

// ---------------------------------------------------------------- embedding
__global__ __launch_bounds__(256) void embed_kernel(
    const int* __restrict__ idx, const float* __restrict__ wte,
    const float* __restrict__ wpe, float* __restrict__ x)
{
    int r = blockIdx.x;             // 0..2047
    int tok = idx[r];
    int pos = r & (TSEQ - 1);
    const float4* a = (const float4*)(wte + (size_t)tok * CDIM);
    const float4* p = (const float4*)(wpe + (size_t)pos * CDIM);
    float4* o = (float4*)(x + (size_t)r * CDIM);
    int t = threadIdx.x;            // CDIM/4 == 256
    float4 av = a[t], pv = p[t];
    o[t] = make_float4(av.x + pv.x, av.y + pv.y, av.z + pv.z, av.w + pv.w);
}

// ---------------------------------------------------------------- layernorm
__global__ __launch_bounds__(256) void ln_kernel(
    const float* __restrict__ x, const float* __restrict__ g,
    const float* __restrict__ b, __hip_bfloat16* __restrict__ out)
{
    int r = blockIdx.x;
    int t = threadIdx.x;
    const float* xr = x + (size_t)r * CDIM;
    float v[4];
#pragma unroll
    for (int i = 0; i < 4; i++) v[i] = xr[t + i * 256];

    __shared__ float red[4];
    int w = t >> 6, lane = t & 63;

    float s = v[0] + v[1] + v[2] + v[3];
    for (int off = 32; off; off >>= 1) s += __shfl_xor(s, off);
    if (lane == 0) red[w] = s;
    __syncthreads();
    float mean = (red[0] + red[1] + red[2] + red[3]) * (1.0f / CDIM);

    float s2 = 0.0f;
#pragma unroll
    for (int i = 0; i < 4; i++) { float d = v[i] - mean; s2 += d * d; }
    for (int off = 32; off; off >>= 1) s2 += __shfl_xor(s2, off);
    __syncthreads();
    if (lane == 0) red[w] = s2;
    __syncthreads();
    float var = (red[0] + red[1] + red[2] + red[3]) * (1.0f / CDIM);
    float rstd = rsqrtf(var + 1e-5f);

#pragma unroll
    for (int i = 0; i < 4; i++) {
        int c = t + i * 256;
        out[(size_t)r * CDIM + c] =
            __float2bfloat16((v[i] - mean) * rstd * g[c] + b[c]);
    }
}

// ---------------------------------------------------------------- transpose+cast
// src fp32 [K][N]  ->  dst bf16 [N][K]
__global__ __launch_bounds__(256) void transcast_kernel(
    const float* __restrict__ src, short* __restrict__ dst, int K, int N)
{
    __shared__ float T[32][33];
    int n0 = blockIdx.x * 32, k0 = blockIdx.y * 32;
    int t = threadIdx.x;
    int r = t >> 3, c = (t & 7) * 4;
    float4 v = *(const float4*)(src + (size_t)(k0 + r) * N + n0 + c);
    T[r][c] = v.x; T[r][c + 1] = v.y; T[r][c + 2] = v.z; T[r][c + 3] = v.w;
    __syncthreads();
    short4 o;
    o.x = f2bs(T[c + 0][r]); o.y = f2bs(T[c + 1][r]);
    o.z = f2bs(T[c + 2][r]); o.w = f2bs(T[c + 3][r]);
    *(short4*)(dst + (size_t)(n0 + r) * K + k0 + c) = o;
}

// ---------------------------------------------------------------- GEMM (NT)
// C[M,N] = A[M,K](bf16) @ B^T where B is [N][K].
// BF32=false: B bf16, staged via global_load_lds.
// BF32=true : B fp32 (lm-head wte), reg-staged + cast.
// Tile BM x 128, BK=32, 256 threads = 4 waves (2x2), wave sub-tile (BM/2) x 64.
// Epilogue: +bias, gelu(exact), +resid(fp32); store fp32 (Cf) or bf16 (Cb).
template <int BM, bool BF32>
__global__ __launch_bounds__(256) void gemm_nt(
    const __hip_bfloat16* __restrict__ A, const void* __restrict__ Bv,
    float* __restrict__ Cf, __hip_bfloat16* __restrict__ Cb,
    const float* __restrict__ bias, const float* __restrict__ resid,
    int M, int N, int K, int do_gelu)
{
    constexpr int MF = BM / 32;          // m-frags per wave
    __shared__ __align__(16) short As[BM * 32];
    __shared__ __align__(16) short Bs[128 * 32];

    int nbx = N >> 7, nby = M / BM;
    int nwg = nbx * nby;
    int bid = blockIdx.x;
    int cpx = nwg >> 3;                  // all our grids have nwg % 8 == 0
    bid = (bid & 7) * cpx + (bid >> 3);  // XCD-aware swizzle
    int bx = bid / nby, by = bid % nby;  // consecutive bids share the B panel
    int m0 = by * BM, n0 = bx * 128;

    int t = threadIdx.x;
    int w = t >> 6, lane = t & 63, g = lane >> 4, l15 = lane & 15;
    int wr = w >> 1, wc = w & 1;

    floatx4 acc[MF][4];
#pragma unroll
    for (int mf = 0; mf < MF; ++mf)
#pragma unroll
        for (int n = 0; n < 4; ++n) acc[mf][n] = (floatx4){0.f, 0.f, 0.f, 0.f};

    const short* Ap = (const short*)A + (size_t)m0 * K;

    for (int k0 = 0; k0 < K; k0 += 32) {
        // stage A: BM x 32 bf16, global_load_lds 16B/lane, linear LDS
#pragma unroll
        for (int i = 0; i < BM / 64; ++i) {
            int c = t + i * 256;
            int row = c >> 2, koff = (c & 3) * 8;
            gload_lds16(Ap + (size_t)row * K + k0 + koff, &As[c * 8]);
        }
        // stage B: 128 x 32
        if (BF32) {
            const float* Bp = (const float*)Bv;
#pragma unroll
            for (int i = 0; i < 2; ++i) {
                int c = t + i * 256;
                int row = c >> 2, koff = (c & 3) * 8;
                const float* src = Bp + (size_t)(n0 + row) * K + k0 + koff;
                float4 f0 = *(const float4*)src;
                float4 f1 = *(const float4*)(src + 4);
                short8 pk;
                pk[0] = f2bs(f0.x); pk[1] = f2bs(f0.y); pk[2] = f2bs(f0.z); pk[3] = f2bs(f0.w);
                pk[4] = f2bs(f1.x); pk[5] = f2bs(f1.y); pk[6] = f2bs(f1.z); pk[7] = f2bs(f1.w);
                *(short8*)&Bs[c * 8] = pk;
            }
        } else {
            const short* Bp = (const short*)Bv;
#pragma unroll
            for (int i = 0; i < 2; ++i) {
                int c = t + i * 256;
                int row = c >> 2, koff = (c & 3) * 8;
                gload_lds16(Bp + (size_t)(n0 + row) * K + k0 + koff, &Bs[c * 8]);
            }
        }
        __syncthreads();

        short8 af[MF], bfr[4];
#pragma unroll
        for (int mf = 0; mf < MF; ++mf)
            af[mf] = *(const short8*)&As[(wr * (BM / 2) + mf * 16 + l15) * 32 + g * 8];
#pragma unroll
        for (int n = 0; n < 4; ++n)
            bfr[n] = *(const short8*)&Bs[(wc * 64 + n * 16 + l15) * 32 + g * 8];
#pragma unroll
        for (int mf = 0; mf < MF; ++mf)
#pragma unroll
            for (int n = 0; n < 4; ++n)
                acc[mf][n] = __builtin_amdgcn_mfma_f32_16x16x32_bf16(
                    af[mf], bfr[n], acc[mf][n], 0, 0, 0);
        __syncthreads();
    }

    // epilogue: D row = g*4 + r within frag, col = l15
#pragma unroll
    for (int mf = 0; mf < MF; ++mf) {
#pragma unroll
        for (int n = 0; n < 4; ++n) {
            int gn = n0 + wc * 64 + n * 16 + l15;
            float bv = bias ? bias[gn] : 0.0f;
#pragma unroll
            for (int r = 0; r < 4; ++r) {
                int gm = m0 + wr * (BM / 2) + mf * 16 + g * 4 + r;
                float v = acc[mf][n][r] + bv;
                if (do_gelu) v = 0.5f * v * (1.0f + erff(v * 0.70710678118654752f));
                if (resid) v += resid[(size_t)gm * N + gn];
                if (Cf) Cf[(size_t)gm * N + gn] = v;
                else    Cb[(size_t)gm * N + gn] = __float2bfloat16(v);
            }
        }
    }
}

// ---------------------------------------------------------------- attention
// Flash-attention with MFMA. One block = one (b,h) x 64 Q-rows; 4 waves,
// each wave owns 16 Q-rows. Online softmax in MFMA D-layout, wave-parallel
// row-reduce via __shfl_xor over the 16-lane column group.
#define KSTR 72   // K LDS row stride (elems): 144B, 16B-aligned, slot-balanced
#define VSTR 66   // V LDS row stride: 132B -> (33k + d/2) mod 32 covers all banks
#define PSTR 72

__global__ __launch_bounds__(256) void attn_kernel(
    const __hip_bfloat16* __restrict__ qkvh, __hip_bfloat16* __restrict__ y)
{
    const short* qkv = (const short*)qkvh;
    __shared__ __align__(16) short Ks[64 * KSTR];
    __shared__ __align__(16) short Vs[64 * VSTR];
    __shared__ __align__(16) short Ps[4][16 * PSTR];   // per-wave P buffer

    int id = blockIdx.x;
    int bh = id & 31;             // (b,h): 2*16 = 32
    int qi = 15 - (id >> 5);      // q-tile, heaviest (most K-tiles) first
    int h = bh & 15, b = bh >> 4;

    int t = threadIdx.x;
    int w = t >> 6, lane = t & 63, g = lane >> 4, l15 = lane & 15;

    const size_t base = (size_t)b * TSEQ * (3 * CDIM);
    const int q0 = qi * 64;
    const int qw = q0 + w * 16;   // wave's first q-row

    // Q fragments in registers: lane holds Q[qw+l15][ks*32 + g*8 + j]
    short8 qf[2];
    {
        const short* qp = qkv + base + (size_t)(qw + l15) * (3 * CDIM) + h * HDIM + g * 8;
        qf[0] = *(const short8*)qp;
        qf[1] = *(const short8*)(qp + 32);
    }

    const short* kp = qkv + base + CDIM + h * HDIM;
    const short* vp = kp + CDIM;

    floatx4 o[4];
    float m[4], lsum[4];
#pragma unroll
    for (int i = 0; i < 4; ++i) {
        o[i] = (floatx4){0.f, 0.f, 0.f, 0.f};
        m[i] = -1e30f; lsum[i] = 0.f;
    }

    short* pw = &Ps[w][0];

    for (int kt = 0; kt <= qi; ++kt) {
        const int k0 = kt * 64;
        __syncthreads();           // prev tile fully consumed
        // stage K,V tile: 64 rows x 128B = 512 x 16B chunks, 2 per thread
#pragma unroll
        for (int c0 = 0; c0 < 2; ++c0) {
            int c = t + c0 * 256;
            int row = c >> 3, off = (c & 7) * 8;
            *(short8*)&Ks[row * KSTR + off] =
                *(const short8*)(kp + (size_t)(k0 + row) * (3 * CDIM) + off);
            union { short8 s; unsigned u[4]; } vv;
            vv.s = *(const short8*)(vp + (size_t)(k0 + row) * (3 * CDIM) + off);
            unsigned* vd = (unsigned*)&Vs[row * VSTR + off];  // 4B-aligned
#pragma unroll
            for (int j = 0; j < 4; ++j) vd[j] = vv.u[j];
        }
        __syncthreads();

        // S = Q K^T : 16x64 in 4 D-frags; lane holds S[4g+r][nt*16+l15]
        floatx4 s[4];
#pragma unroll
        for (int nt = 0; nt < 4; ++nt) s[nt] = (floatx4){0.f, 0.f, 0.f, 0.f};
#pragma unroll
        for (int ks = 0; ks < 2; ++ks) {
#pragma unroll
            for (int nt = 0; nt < 4; ++nt) {
                short8 kf = *(const short8*)&Ks[(nt * 16 + l15) * KSTR + ks * 32 + g * 8];
                s[nt] = __builtin_amdgcn_mfma_f32_16x16x32_bf16(qf[ks], kf, s[nt], 0, 0, 0);
            }
        }

        // scale + causal mask (diagonal tile only)
        const float scale = 0.125f;   // 1/sqrt(64)
        if (kt == qi) {
#pragma unroll
            for (int nt = 0; nt < 4; ++nt) {
                int kk = k0 + nt * 16 + l15;
#pragma unroll
                for (int r = 0; r < 4; ++r) {
                    int qq = qw + 4 * g + r;
                    s[nt][r] = (kk <= qq) ? s[nt][r] * scale : -1e30f;
                }
            }
        } else {
#pragma unroll
            for (int nt = 0; nt < 4; ++nt)
#pragma unroll
                for (int r = 0; r < 4; ++r) s[nt][r] *= scale;
        }

        // wave-parallel row max over 64 keys (4 frags in-lane + xor over 16 lanes)
        float mk[4];
#pragma unroll
        for (int r = 0; r < 4; ++r)
            mk[r] = fmaxf(fmaxf(s[0][r], s[1][r]), fmaxf(s[2][r], s[3][r]));
#pragma unroll
        for (int off = 1; off < 16; off <<= 1)
#pragma unroll
            for (int r = 0; r < 4; ++r)
                mk[r] = fmaxf(mk[r], __shfl_xor(mk[r], off));

        float corr[4], psum[4];
#pragma unroll
        for (int r = 0; r < 4; ++r) {
            float mn = fmaxf(m[r], mk[r]);
            corr[r] = __expf(m[r] - mn);
            m[r] = mn;
            psum[r] = 0.f;
        }
#pragma unroll
        for (int nt = 0; nt < 4; ++nt)
#pragma unroll
            for (int r = 0; r < 4; ++r) {
                float p = __expf(s[nt][r] - m[r]);
                s[nt][r] = p;
                psum[r] += p;
            }
#pragma unroll
        for (int off = 1; off < 16; off <<= 1)
#pragma unroll
            for (int r = 0; r < 4; ++r) psum[r] += __shfl_xor(psum[r], off);
#pragma unroll
        for (int r = 0; r < 4; ++r) lsum[r] = lsum[r] * corr[r] + psum[r];
#pragma unroll
        for (int nt = 0; nt < 4; ++nt)
#pragma unroll
            for (int r = 0; r < 4; ++r) o[nt][r] *= corr[r];

        // P (D-layout) -> wave-private LDS as bf16 (A-fragment transpose)
#pragma unroll
        for (int nt = 0; nt < 4; ++nt)
#pragma unroll
            for (int r = 0; r < 4; ++r)
                pw[(4 * g + r) * PSTR + nt * 16 + l15] = f2bs(s[nt][r]);

        // O += P V
#pragma unroll
        for (int ks = 0; ks < 2; ++ks) {
            short8 pf = *(const short8*)&pw[l15 * PSTR + ks * 32 + g * 8];
#pragma unroll
            for (int nt = 0; nt < 4; ++nt) {
                short8 vf;
#pragma unroll
                for (int j = 0; j < 8; ++j)
                    vf[j] = Vs[(ks * 32 + g * 8 + j) * VSTR + nt * 16 + l15];
                o[nt] = __builtin_amdgcn_mfma_f32_16x16x32_bf16(pf, vf, o[nt], 0, 0, 0);
            }
        }
    }

    // epilogue: y[b, q, h*64 + d] = o / lsum
#pragma unroll
    for (int r = 0; r < 4; ++r) {
        float inv = 1.0f / lsum[r];
        int gq = qw + 4 * g + r;
        __hip_bfloat16* yr = y + (size_t)(b * TSEQ + gq) * CDIM + h * HDIM;
#pragma unroll
        for (int nt = 0; nt < 4; ++nt)
            yr[nt * 16 + l15] = __float2bfloat16(o[nt][r] * inv);
    }
}

// ---------------------------------------------------------------- loss
__global__ __launch_bounds__(256) void loss_rows_kernel(
    const float* __restrict__ logits, const int* __restrict__ targets,
    float* __restrict__ out)
{
    int r = blockIdx.x, t = threadIdx.x;
    const float* row = logits + (size_t)r * VOCAB;
    __shared__ float red[4];
    int w = t >> 6, lane = t & 63;

    float mx = -1e30f;
    for (int c = t; c < VOCAB; c += 256) mx = fmaxf(mx, row[c]);
    for (int off = 32; off; off >>= 1) mx = fmaxf(mx, __shfl_xor(mx, off));
    if (lane == 0) red[w] = mx;
    __syncthreads();
    mx = fmaxf(fmaxf(red[0], red[1]), fmaxf(red[2], red[3]));

    float s = 0.0f;
    for (int c = t; c < VOCAB; c += 256) s += __expf(row[c] - mx);
    for (int off = 32; off; off >>= 1) s += __shfl_xor(s, off);
    __syncthreads();
    if (lane == 0) red[w] = s;
    __syncthreads();
    s = red[0] + red[1] + red[2] + red[3];

    if (t == 0) out[r] = logf(s) + mx - row[targets[r]];
}

__global__ __launch_bounds__(256) void loss_final_kernel(
    const float* __restrict__ lr, float* __restrict__ out)
{
    int t = threadIdx.x;
    float s = 0.0f;
    for (int c = t; c < ROWS; c += 256) s += lr[c];
    for (int off = 32; off; off >>= 1) s += __shfl_xor(s, off);
    __shared__ float red[4];
    int w = t >> 6, lane = t & 63;
    if (lane == 0) red[w] = s;
    __syncthreads();
    if (t == 0) out[0] = (red[0] + red[1] + red[2] + red[3]) * (1.0f / ROWS);
}

// ---------------------------------------------------------------- launch
extern "C" void kernel_launch(void* const* d_in, const int* in_sizes, int n_in,
                              void* d_out, int out_size, void* d_ws, size_t ws_size,
                              hipStream_t stream)
{
    const int*   idx     = (const int*)d_in[0];
    const int*   targets = (const int*)d_in[1];
    const float* wte     = (const float*)d_in[2];
    const float* wpe     = (const float*)d_in[3];
    const float* ln1_g   = (const float*)d_in[4];
    const float* ln1_b   = (const float*)d_in[5];
    const float* qkv_w   = (const float*)d_in[6];
    const float* aproj_w = (const float*)d_in[7];
    const float* ln2_g   = (const float*)d_in[8];
    const float* ln2_b   = (const float*)d_in[9];
    const float* fc_w    = (const float*)d_in[10];
    const float* fc_b    = (const float*)d_in[11];
    const float* mproj_w = (const float*)d_in[12];
    const float* mproj_b = (const float*)d_in[13];
    const float* lnf_g   = (const float*)d_in[14];
    const float* lnf_b   = (const float*)d_in[15];

    char* p = (char*)d_ws;
    float* x             = (float*)p;           p += (size_t)ROWS * CDIM * 4;
    __hip_bfloat16* qkvb = (__hip_bfloat16*)p;  p += (size_t)ROWS * 3 * CDIM * 2;
    __hip_bfloat16* h_bf = (__hip_bfloat16*)p;  p += (size_t)ROWS * CDIM * 2;
    __hip_bfloat16* g_bf = (__hip_bfloat16*)p;  p += (size_t)ROWS * DFFDIM * 2;
    __hip_bfloat16* y_bf = (__hip_bfloat16*)p;  p += (size_t)ROWS * CDIM * 2;
    float* lrow          = (float*)p;           p += (size_t)ROWS * 4;
    short* wT            = (short*)p;           p += (size_t)DFFDIM * CDIM * 2;

    float* logits = (float*)d_out;

    embed_kernel<<<ROWS, 256, 0, stream>>>(idx, wte, wpe, x);

    for (int l = 0; l < NLAYERS; l++) {
        ln_kernel<<<ROWS, 256, 0, stream>>>(x, ln1_g + l * CDIM, ln1_b + l * CDIM, h_bf);

        // qkv: B = qkv_w[l] (C x 3C) -> wT (3C x C)
        transcast_kernel<<<dim3(3 * CDIM / 32, CDIM / 32), 256, 0, stream>>>(
            qkv_w + (size_t)l * CDIM * 3 * CDIM, wT, CDIM, 3 * CDIM);
        gemm_nt<128, false><<<(3 * CDIM / 128) * (ROWS / 128), 256, 0, stream>>>(
            h_bf, wT, nullptr, qkvb, nullptr, nullptr, ROWS, 3 * CDIM, CDIM, 0);

        attn_kernel<<<32 * (TSEQ / 64), 256, 0, stream>>>(qkvb, y_bf);

        // aproj: B = aproj_w[l] (C x C) -> wT (C x C)
        transcast_kernel<<<dim3(CDIM / 32, CDIM / 32), 256, 0, stream>>>(
            aproj_w + (size_t)l * CDIM * CDIM, wT, CDIM, CDIM);
        gemm_nt<64, false><<<(CDIM / 128) * (ROWS / 64), 256, 0, stream>>>(
            y_bf, wT, x, nullptr, nullptr, x, ROWS, CDIM, CDIM, 0);

        ln_kernel<<<ROWS, 256, 0, stream>>>(x, ln2_g + l * CDIM, ln2_b + l * CDIM, h_bf);

        // fc: B = fc_w[l] (C x DFF) -> wT (DFF x C)
        transcast_kernel<<<dim3(DFFDIM / 32, CDIM / 32), 256, 0, stream>>>(
            fc_w + (size_t)l * CDIM * DFFDIM, wT, CDIM, DFFDIM);
        gemm_nt<128, false><<<(DFFDIM / 128) * (ROWS / 128), 256, 0, stream>>>(
            h_bf, wT, nullptr, g_bf, fc_b + l * DFFDIM, nullptr, ROWS, DFFDIM, CDIM, 1);

        // mproj: B = mproj_w[l] (DFF x C) -> wT (C x DFF)
        transcast_kernel<<<dim3(CDIM / 32, DFFDIM / 32), 256, 0, stream>>>(
            mproj_w + (size_t)l * DFFDIM * CDIM, wT, DFFDIM, CDIM);
        gemm_nt<64, false><<<(CDIM / 128) * (ROWS / 64), 256, 0, stream>>>(
            g_bf, wT, x, nullptr, mproj_b + l * CDIM, x, ROWS, CDIM, DFFDIM, 0);
    }

    ln_kernel<<<ROWS, 256, 0, stream>>>(x, lnf_g, lnf_b, h_bf);
    // lm-head: B = wte (V x C) fp32, already [N][K] -> reg-staged cast path
    gemm_nt<128, true><<<(VOCAB / 128) * (ROWS / 128), 256, 0, stream>>>(
        h_bf, wte, logits, nullptr, nullptr, nullptr, ROWS, VOCAB, CDIM, 0);

    loss_rows_kernel<<<ROWS, 256, 0, stream>>>(logits, targets, lrow);
    loss_final_kernel<<<1, 256, 0, stream>>>(lrow, logits + (size_t)ROWS * VOCAB);
}